// Round 3
// baseline (490.296 us; speedup 1.0000x reference)
//
#include <hip/hip_runtime.h>
#include <hip/hip_bf16.h>

typedef unsigned int u32;
typedef unsigned short u16;
typedef unsigned long long u64;

#define NBINS 65536
#define MAXB 8

// Monotone map: fp32 bits -> u32 key, ascending in float value (no NaNs in data).
__device__ __forceinline__ u32 mono(float f) {
    u32 u = __float_as_uint(f);
    return (u & 0x80000000u) ? ~u : (u | 0x80000000u);
}

// K-hist A: per-batch histogram of high 16 key bits.
__global__ void k_histA(const float* __restrict__ scores, const int* __restrict__ bids,
                        u32* __restrict__ hist, int N) {
    int i = blockIdx.x * blockDim.x + threadIdx.x;
    if (i >= N) return;
    u32 k = mono(scores[i]) >> 16;
    atomicAdd(&hist[(u32)bids[i] * NBINS + k], 1u);
}

// K-hist B: per-batch histogram of low 16 key bits, restricted to high bin H*.
__global__ void k_histB(const float* __restrict__ scores, const int* __restrict__ bids,
                        const u32* __restrict__ Hstar, u32* __restrict__ hist, int N) {
    int i = blockIdx.x * blockDim.x + threadIdx.x;
    if (i >= N) return;
    int b = bids[i];
    u32 key = mono(scores[i]);
    if ((key >> 16) == Hstar[b])
        atomicAdd(&hist[(u32)b * NBINS + (key & 0xFFFFu)], 1u);
}

// Suffix select: largest bin index B with suffix_count(B) >= target.
// remaining_out = target - suffix_count(B+1)  (count needed inside bin B).
// Returns -1 if total < target (deficient batch).
__device__ int suffix_select(const u32* __restrict__ h, u32 target, u32& remaining_out) {
    __shared__ u32 s[256];
    __shared__ int cc_s;
    __shared__ u32 run_s;
    __shared__ int res_s;
    __shared__ u32 rem_s;
    const int t = threadIdx.x;
    if (t == 0) cc_s = -1;
    u32 tot = 0;
    const uint4* hv = (const uint4*)(h + t * 256);
#pragma unroll 8
    for (int q = 0; q < 64; ++q) { uint4 v = hv[q]; tot += v.x + v.y + v.z + v.w; }
    s[t] = tot;
    __syncthreads();
    for (int off = 1; off < 256; off <<= 1) {
        u32 add = (t + off < 256) ? s[t + off] : 0u;
        __syncthreads();
        s[t] += add;
        __syncthreads();
    }
    u32 nxt = (t == 255) ? 0u : s[t + 1];
    if (s[t] >= target && nxt < target) { cc_s = t; run_s = nxt; }
    __syncthreads();
    int cc = cc_s;
    if (cc < 0) { remaining_out = 0; return -1; }  // total < target
    u32 running = run_s;
    u32 v = h[cc * 256 + t];
    __syncthreads();
    s[t] = v;
    __syncthreads();
    for (int off = 1; off < 256; off <<= 1) {
        u32 add = (t + off < 256) ? s[t + off] : 0u;
        __syncthreads();
        s[t] += add;
        __syncthreads();
    }
    u32 nxt2 = (t == 255) ? 0u : s[t + 1];
    if (running + s[t] >= target && running + nxt2 < target) {
        res_s = cc * 256 + t;
        rem_s = target - (running + nxt2);
    }
    __syncthreads();
    remaining_out = rem_s;
    return res_s;
}

__global__ void k_scanA(const u32* __restrict__ hist, const int* __restrict__ kptr,
                        u32* __restrict__ Hstar, u32* __restrict__ rB,
                        u32* __restrict__ thresh) {
    int b = blockIdx.x;
    u32 rem;
    int bin = suffix_select(hist + (size_t)b * NBINS, (u32)kptr[0], rem);
    if (threadIdx.x == 0) {
        if (bin < 0) { Hstar[b] = 0xFFFFFFFFu; rB[b] = 0u; thresh[b] = 0u; }
        else { Hstar[b] = (u32)bin; rB[b] = rem; }
    }
}

__global__ void k_scanB(const u32* __restrict__ hist, const u32* __restrict__ Hstar,
                        const u32* __restrict__ rB, u32* __restrict__ thresh) {
    int b = blockIdx.x;
    u32 H = Hstar[b];
    if (H == 0xFFFFFFFFu) return;  // deficient: thresh already 0 (all pass)
    u32 rem;
    int bin = suffix_select(hist + (size_t)b * NBINS, rB[b], rem);
    if (threadIdx.x == 0) thresh[b] = (H << 16) | (u32)bin;
}

// K-mask: mask, write default rows (fp32) for pruned points, ballot-compact survivors.
__global__ void k_mask(const float* __restrict__ scores, const int* __restrict__ bids,
                       const u32* __restrict__ thresh, const float* __restrict__ bcls,
                       float* __restrict__ out, u32* __restrict__ surv,
                       u32* __restrict__ counter, int N) {
    int i = blockIdx.x * blockDim.x + threadIdx.x;
    bool alive = false;
    if (i < N) alive = mono(scores[i]) >= thresh[bids[i]];
    u64 m = __ballot(alive);
    int lane = threadIdx.x & 63;
    int cnt = __popcll(m);
    if (cnt) {
        u32 base = 0;
        if (lane == 0) base = atomicAdd(counter, (u32)cnt);
        base = (u32)__shfl((int)base, 0, 64);
        if (alive) {
            u32 pos = base + (u32)__popcll(m & ((1ull << lane) - 1ull));
            surv[pos] = (u32)i;
        }
    }
    if (i < N && !alive) {
        // pruned row: bbox = exp(0) = 1.0, cls = b_cls
        __align__(16) float o[24];
#pragma unroll
        for (int j = 0; j < 6; ++j) o[j] = 1.0f;
#pragma unroll
        for (int j = 0; j < 18; ++j) o[6 + j] = bcls[j];
        float4* op = (float4*)(out + (size_t)i * 24);
        const float4* src = (const float4*)o;
#pragma unroll
        for (int q = 0; q < 6; ++q) op[q] = src[q];
    }
}

// K-matmul: survivor-only [1,256]@[256,24]. Weights (scale folded) in LDS fp32;
// 2 points per thread to amortize broadcast LDS weight reads. Output fp32.
__global__ __launch_bounds__(256) void k_matmul(
    const float* __restrict__ feats, const float* __restrict__ wreg,
    const float* __restrict__ wcls, const float* __restrict__ bcls,
    const float* __restrict__ scalep, const u32* __restrict__ surv,
    const u32* __restrict__ counter, float* __restrict__ out) {
    const u32 count = counter[0];
    if ((u32)(blockIdx.x * 512) >= count) return;

    __shared__ float W[256 * 24];
    float scl = scalep[0];
    for (int idx = threadIdx.x; idx < 256 * 24; idx += 256) {
        int c = idx / 24, j = idx - c * 24;
        W[idx] = (j < 6) ? scl * wreg[c * 6 + j] : wcls[c * 18 + (j - 6)];
    }
    __syncthreads();

    u32 g = blockIdx.x * 256 + threadIdx.x;
    u32 t0 = 2u * g, t1 = 2u * g + 1u;
    if (t0 >= count) return;
    bool a1 = (t1 < count);
    u32 i0 = surv[t0];
    u32 i1 = a1 ? surv[t1] : i0;
    const float* r0 = feats + (size_t)i0 * 256;
    const float* r1 = feats + (size_t)i1 * 256;

    float acc0[24], acc1[24];
#pragma unroll
    for (int j = 0; j < 24; ++j) { acc0[j] = 0.f; acc1[j] = 0.f; }

    for (int c0 = 0; c0 < 256; c0 += 8) {
        float4 p0a = *(const float4*)(r0 + c0);
        float4 p0b = *(const float4*)(r0 + c0 + 4);
        float4 p1a = *(const float4*)(r1 + c0);
        float4 p1b = *(const float4*)(r1 + c0 + 4);
        float f0[8] = {p0a.x, p0a.y, p0a.z, p0a.w, p0b.x, p0b.y, p0b.z, p0b.w};
        float f1[8] = {p1a.x, p1a.y, p1a.z, p1a.w, p1b.x, p1b.y, p1b.z, p1b.w};
#pragma unroll
        for (int t = 0; t < 8; ++t) {
            const float* wr = &W[(c0 + t) * 24];
#pragma unroll
            for (int j = 0; j < 24; j += 4) {
                float4 w4 = *(const float4*)(wr + j);
                acc0[j + 0] += f0[t] * w4.x;
                acc0[j + 1] += f0[t] * w4.y;
                acc0[j + 2] += f0[t] * w4.z;
                acc0[j + 3] += f0[t] * w4.w;
                acc1[j + 0] += f1[t] * w4.x;
                acc1[j + 1] += f1[t] * w4.y;
                acc1[j + 2] += f1[t] * w4.z;
                acc1[j + 3] += f1[t] * w4.w;
            }
        }
    }

    __align__(16) float o[24];
#pragma unroll
    for (int j = 0; j < 6; ++j) o[j] = __expf(acc0[j]);
#pragma unroll
    for (int j = 0; j < 18; ++j) o[6 + j] = acc0[6 + j] + bcls[j];
    {
        float4* op = (float4*)(out + (size_t)i0 * 24);
        const float4* src = (const float4*)o;
#pragma unroll
        for (int q = 0; q < 6; ++q) op[q] = src[q];
    }
    if (a1) {
#pragma unroll
        for (int j = 0; j < 6; ++j) o[j] = __expf(acc1[j]);
#pragma unroll
        for (int j = 0; j < 18; ++j) o[6 + j] = acc1[6 + j] + bcls[j];
        float4* op = (float4*)(out + (size_t)i1 * 24);
        const float4* src = (const float4*)o;
#pragma unroll
        for (int q = 0; q < 6; ++q) op[q] = src[q];
    }
}

extern "C" void kernel_launch(void* const* d_in, const int* in_sizes, int n_in,
                              void* d_out, int out_size, void* d_ws, size_t ws_size,
                              hipStream_t stream) {
    const float* feats  = (const float*)d_in[0];
    const float* scores = (const float*)d_in[1];
    const float* wreg   = (const float*)d_in[2];
    const float* wcls   = (const float*)d_in[3];
    const float* bcls   = (const float*)d_in[4];
    const float* scalep = (const float*)d_in[5];
    const int*   bids   = (const int*)d_in[6];
    const int*   kptr   = (const int*)d_in[8];  // pts_threshold
    float* out = (float*)d_out;                 // output fp32
    const int N = in_sizes[6];                  // batch_ids element count

    // ws layout (u32 units): [0..63] counter+pad | [64..) hist (8*65536)
    //                        | thresh[16] | Hstar[16] | rB[16] | surv[N]
    u32* counter = (u32*)d_ws;
    u32* hist    = counter + 64;
    u32* thresh  = hist + (size_t)MAXB * NBINS;
    u32* Hstar   = thresh + 16;
    u32* rB      = Hstar + 16;
    u32* surv    = rB + 16;

    size_t zero1 = (64 + (size_t)MAXB * NBINS) * sizeof(u32);  // counter + hist
    hipMemsetAsync(d_ws, 0, zero1, stream);

    int nb = (N + 255) / 256;
    k_histA<<<nb, 256, 0, stream>>>(scores, bids, hist, N);
    k_scanA<<<MAXB, 256, 0, stream>>>(hist, kptr, Hstar, rB, thresh);
    // re-zero hist region for pass B
    hipMemsetAsync(hist, 0, (size_t)MAXB * NBINS * sizeof(u32), stream);
    k_histB<<<nb, 256, 0, stream>>>(scores, bids, Hstar, hist, N);
    k_scanB<<<MAXB, 256, 0, stream>>>(hist, Hstar, rB, thresh);
    k_mask<<<nb, 256, 0, stream>>>(scores, bids, thresh, bcls, out, surv, counter, N);
    k_matmul<<<(N + 511) / 512, 256, 0, stream>>>(feats, wreg, wcls, bcls, scalep, surv, counter, out);
}

// Round 4
// 414.591 us; speedup vs baseline: 1.1826x; 1.1826x over previous
//
#include <hip/hip_runtime.h>

typedef unsigned int u32;
typedef unsigned long long u64;

#define NBINS 65536
#define MAXB 8

// Monotone map: fp32 bits -> u32 key, ascending in float value (no NaNs in data).
__device__ __forceinline__ u32 mono(float f) {
    u32 u = __float_as_uint(f);
    return (u & 0x80000000u) ? ~u : (u | 0x80000000u);
}

// K-hist A: per-batch histogram of high 16 key bits.
__global__ void k_histA(const float* __restrict__ scores, const int* __restrict__ bids,
                        u32* __restrict__ hist, int N) {
    int i = blockIdx.x * blockDim.x + threadIdx.x;
    if (i >= N) return;
    atomicAdd(&hist[(u32)bids[i] * NBINS + (mono(scores[i]) >> 16)], 1u);
}

// K-hist B: per-batch histogram of low 16 key bits, restricted to high bin H*.
__global__ void k_histB(const float* __restrict__ scores, const int* __restrict__ bids,
                        const u32* __restrict__ Hstar, u32* __restrict__ hist, int N) {
    int i = blockIdx.x * blockDim.x + threadIdx.x;
    if (i >= N) return;
    int b = bids[i];
    u32 key = mono(scores[i]);
    if ((key >> 16) == Hstar[b])
        atomicAdd(&hist[(u32)b * NBINS + (key & 0xFFFFu)], 1u);
}

// Suffix select: largest bin index B with suffix_count(B) >= target.
// remaining_out = target - suffix_count(B+1). Returns -1 if total < target.
__device__ int suffix_select(const u32* __restrict__ h, u32 target, u32& remaining_out) {
    __shared__ u32 s[256];
    __shared__ int cc_s;
    __shared__ u32 run_s;
    __shared__ int res_s;
    __shared__ u32 rem_s;
    const int t = threadIdx.x;
    if (t == 0) cc_s = -1;
    u32 tot = 0;
    const uint4* hv = (const uint4*)(h + t * 256);
#pragma unroll 8
    for (int q = 0; q < 64; ++q) { uint4 v = hv[q]; tot += v.x + v.y + v.z + v.w; }
    s[t] = tot;
    __syncthreads();
    for (int off = 1; off < 256; off <<= 1) {
        u32 add = (t + off < 256) ? s[t + off] : 0u;
        __syncthreads();
        s[t] += add;
        __syncthreads();
    }
    u32 nxt = (t == 255) ? 0u : s[t + 1];
    if (s[t] >= target && nxt < target) { cc_s = t; run_s = nxt; }
    __syncthreads();
    int cc = cc_s;
    if (cc < 0) { remaining_out = 0; return -1; }
    u32 running = run_s;
    u32 v = h[cc * 256 + t];
    __syncthreads();
    s[t] = v;
    __syncthreads();
    for (int off = 1; off < 256; off <<= 1) {
        u32 add = (t + off < 256) ? s[t + off] : 0u;
        __syncthreads();
        s[t] += add;
        __syncthreads();
    }
    u32 nxt2 = (t == 255) ? 0u : s[t + 1];
    if (running + s[t] >= target && running + nxt2 < target) {
        res_s = cc * 256 + t;
        rem_s = target - (running + nxt2);
    }
    __syncthreads();
    remaining_out = rem_s;
    return res_s;
}

__global__ void k_scanA(const u32* __restrict__ hist, const int* __restrict__ kptr,
                        u32* __restrict__ Hstar, u32* __restrict__ rB,
                        u32* __restrict__ thresh) {
    int b = blockIdx.x;
    u32 rem;
    int bin = suffix_select(hist + (size_t)b * NBINS, (u32)kptr[0], rem);
    if (threadIdx.x == 0) {
        if (bin < 0) { Hstar[b] = 0xFFFFFFFFu; rB[b] = 0u; thresh[b] = 0u; }
        else { Hstar[b] = (u32)bin; rB[b] = rem; }
    }
}

__global__ void k_scanB(const u32* __restrict__ hist, const u32* __restrict__ Hstar,
                        const u32* __restrict__ rB, u32* __restrict__ thresh) {
    int b = blockIdx.x;
    u32 H = Hstar[b];
    if (H == 0xFFFFFFFFu) return;  // deficient: thresh stays 0 (all pass)
    u32 rem;
    int bin = suffix_select(hist + (size_t)b * NBINS, rB[b], rem);
    if (threadIdx.x == 0) thresh[b] = (H << 16) | (u32)bin;
}

// Fused mask + matmul: each block owns 512 points. Phase 1: decide alive,
// write default rows for dead, LDS-compact alive ids. Phase 2: dense matmul
// over the block's survivors (weights+scale staged in LDS).
__global__ __launch_bounds__(256) void k_fused(
    const float* __restrict__ feats, const float* __restrict__ scores,
    const int* __restrict__ bids, const u32* __restrict__ thresh,
    const float* __restrict__ wreg, const float* __restrict__ wcls,
    const float* __restrict__ bcls, const float* __restrict__ scalep,
    float* __restrict__ out, int N) {

    __shared__ float W[256 * 24];     // weights, scale folded into first 6 cols
    __shared__ u32 alive_idx[512];
    __shared__ u32 nAlive;
    __shared__ float defrow[24];      // pruned-row constants: {1.0 x6, b_cls}

    float scl = scalep[0];
    for (int idx = threadIdx.x; idx < 256 * 24; idx += 256) {
        int c = idx / 24, j = idx - c * 24;
        W[idx] = (j < 6) ? scl * wreg[c * 6 + j] : wcls[c * 18 + (j - 6)];
    }
    if (threadIdx.x == 0) nAlive = 0;
    if (threadIdx.x < 24) defrow[threadIdx.x] = (threadIdx.x < 6) ? 1.0f : bcls[threadIdx.x - 6];
    __syncthreads();

    const int base = blockIdx.x * 512;
#pragma unroll
    for (int q = 0; q < 2; ++q) {
        int i = base + threadIdx.x + q * 256;
        if (i < N) {
            bool alive = mono(scores[i]) >= thresh[bids[i]];
            if (alive) {
                u32 p = atomicAdd(&nAlive, 1u);
                alive_idx[p] = (u32)i;
            } else {
                float4* op = (float4*)(out + (size_t)i * 24);
                const float4* s4 = (const float4*)defrow;
#pragma unroll
                for (int w = 0; w < 6; ++w) op[w] = s4[w];
            }
        }
    }
    __syncthreads();
    const u32 cnt = nAlive;

    for (u32 r = threadIdx.x; r < cnt; r += 256) {
        u32 i = alive_idx[r];
        const float* row = feats + (size_t)i * 256;
        float acc[24];
#pragma unroll
        for (int j = 0; j < 24; ++j) acc[j] = 0.f;
        for (int c0 = 0; c0 < 256; c0 += 8) {
            float4 a = *(const float4*)(row + c0);
            float4 b = *(const float4*)(row + c0 + 4);
            float f[8] = {a.x, a.y, a.z, a.w, b.x, b.y, b.z, b.w};
#pragma unroll
            for (int t = 0; t < 8; ++t) {
                const float* wr = &W[(c0 + t) * 24];
#pragma unroll
                for (int j = 0; j < 24; j += 4) {
                    float4 w4 = *(const float4*)(wr + j);
                    acc[j + 0] += f[t] * w4.x;
                    acc[j + 1] += f[t] * w4.y;
                    acc[j + 2] += f[t] * w4.z;
                    acc[j + 3] += f[t] * w4.w;
                }
            }
        }
        __align__(16) float o[24];
#pragma unroll
        for (int j = 0; j < 6; ++j) o[j] = __expf(acc[j]);
#pragma unroll
        for (int j = 0; j < 18; ++j) o[6 + j] = acc[6 + j] + defrow[6 + j];
        float4* op = (float4*)(out + (size_t)i * 24);
        const float4* s4 = (const float4*)o;
#pragma unroll
        for (int w = 0; w < 6; ++w) op[w] = s4[w];
    }
}

extern "C" void kernel_launch(void* const* d_in, const int* in_sizes, int n_in,
                              void* d_out, int out_size, void* d_ws, size_t ws_size,
                              hipStream_t stream) {
    const float* feats  = (const float*)d_in[0];
    const float* scores = (const float*)d_in[1];
    const float* wreg   = (const float*)d_in[2];
    const float* wcls   = (const float*)d_in[3];
    const float* bcls   = (const float*)d_in[4];
    const float* scalep = (const float*)d_in[5];
    const int*   bids   = (const int*)d_in[6];
    const int*   kptr   = (const int*)d_in[8];  // pts_threshold
    float* out = (float*)d_out;
    const int N = in_sizes[6];

    // ws layout (u32 units): histA[8*65536] | histB[8*65536] | thresh[16] | Hstar[16] | rB[16]
    u32* histA  = (u32*)d_ws;
    u32* histB  = histA + (size_t)MAXB * NBINS;
    u32* thresh = histB + (size_t)MAXB * NBINS;
    u32* Hstar  = thresh + 16;
    u32* rB     = Hstar + 16;

    hipMemsetAsync(d_ws, 0, (2 * (size_t)MAXB * NBINS) * sizeof(u32), stream);

    int nb = (N + 255) / 256;
    k_histA<<<nb, 256, 0, stream>>>(scores, bids, histA, N);
    k_scanA<<<MAXB, 256, 0, stream>>>(histA, kptr, Hstar, rB, thresh);
    k_histB<<<nb, 256, 0, stream>>>(scores, bids, Hstar, histB, N);
    k_scanB<<<MAXB, 256, 0, stream>>>(histB, Hstar, rB, thresh);
    k_fused<<<(N + 511) / 512, 256, 0, stream>>>(feats, scores, bids, thresh,
                                                 wreg, wcls, bcls, scalep, out, N);
}